// Round 6
// baseline (252.747 us; speedup 1.0000x reference)
//
#include <hip/hip_runtime.h>
#include <math.h>

// Problem constants (fixed by setup_inputs)
#define BB 64
#define CC 512
#define CR 32
#define HW 3136
#define HW4 784                    // HW/4 float4 per plane
#define GROUP_B 32                 // batches per L3-resident group (205.6 MB < 256 MB L3)
#define NGROUP (BB / GROUP_B)      // 2
#define PLANES_G (GROUP_B * CC)    // 16384 planes per group
#define WPB 4                      // waves per block (256 threads)

typedef float f32x4 __attribute__((ext_vector_type(4)));

// ---------------------------------------------------------------------------
// Kernel 1: global average pool. One WAVE per plane. 4 independent f32x4
// accumulators -> 12 loads in flight per unrolled step (MLP for HBM latency).
// ---------------------------------------------------------------------------
__global__ __launch_bounds__(256) void se_pool(const float* __restrict__ x,
                                               float* __restrict__ s, int group) {
    const int wave = threadIdx.x >> 6;
    const int lane = threadIdx.x & 63;
    const int p = group * PLANES_G + blockIdx.x * WPB + wave;
    const f32x4* x4 = reinterpret_cast<const f32x4*>(x) + (size_t)p * HW4;

    f32x4 a0 = {0,0,0,0}, a1 = {0,0,0,0}, a2 = {0,0,0,0}, a3 = {0,0,0,0};
    int i = lane;
    #pragma unroll
    for (int k = 0; k < 3; ++k) {                  // covers lane + {0..11}*64
        a0 += x4[i];
        a1 += x4[i + 64];
        a2 += x4[i + 128];
        a3 += x4[i + 192];
        i += 256;
    }
    if (lane < 16) a0 += x4[768 + lane];           // tail: 784 = 12*64 + 16

    f32x4 tv = (a0 + a1) + (a2 + a3);
    float acc = (tv.x + tv.y) + (tv.z + tv.w);
    #pragma unroll
    for (int off = 32; off > 0; off >>= 1)
        acc += __shfl_down(acc, off, 64);
    if (lane == 0)
        s[p] = acc * (1.0f / (float)HW);
}

// ---------------------------------------------------------------------------
// Kernel 2: FC bottleneck + sigmoid gate. One block per batch of this group.
// ---------------------------------------------------------------------------
__global__ __launch_bounds__(256) void se_fc(
    const float* __restrict__ s,
    const float* __restrict__ w1, const float* __restrict__ b1,
    const float* __restrict__ w2, const float* __restrict__ b2,
    float* __restrict__ g, int group)
{
    const int b = group * GROUP_B + blockIdx.x;
    const int t = threadIdx.x;
    __shared__ float s_sh[CC];
    __shared__ float h_sh[CR];

    s_sh[t]       = s[b * CC + t];
    s_sh[t + 256] = s[b * CC + t + 256];
    __syncthreads();

    // h[r] = relu(b1[r] + sum_c s[c]*w1[r,c]); 8 threads per row r.
    const int r = t >> 3, part = t & 7;
    const float* wr = w1 + r * CC;
    float ha = 0.0f;
    #pragma unroll
    for (int k = 0; k < CC / 8; ++k) {
        const int c = part + 8 * k;
        ha = fmaf(s_sh[c], wr[c], ha);
    }
    ha += __shfl_down(ha, 4, 8);
    ha += __shfl_down(ha, 2, 8);
    ha += __shfl_down(ha, 1, 8);
    if (part == 0) h_sh[r] = fmaxf(ha + b1[r], 0.0f);
    __syncthreads();

    // g[b, c2] = sigmoid(b2[c2] + sum_r h[r]*w2[c2,r]); 2 gates per thread.
    #pragma unroll
    for (int j = 0; j < 2; ++j) {
        const int c2 = t + j * 256;
        float a2 = b2[c2];
        const float* w2r = w2 + c2 * CR;
        #pragma unroll
        for (int rr = 0; rr < CR; ++rr)
            a2 = fmaf(h_sh[rr], w2r[rr], a2);
        g[b * CC + c2] = 1.0f / (1.0f + expf(-a2));
    }
}

// ---------------------------------------------------------------------------
// Kernel 3: scale. One WAVE per plane; x chunk is L3-resident from the pool
// pass. NORMAL stores (NT suspected slow); 2x unrolled for load MLP.
// ---------------------------------------------------------------------------
__global__ __launch_bounds__(256) void se_scale(
    const float* __restrict__ x, const float* __restrict__ g,
    float* __restrict__ out, int group)
{
    const int wave = threadIdx.x >> 6;
    const int lane = threadIdx.x & 63;
    const int p = group * PLANES_G + blockIdx.x * WPB + wave;
    const float gv = g[p];                         // same addr across wave -> broadcast
    const size_t base = (size_t)p * HW4;
    const f32x4* x4 = reinterpret_cast<const f32x4*>(x) + base;
    f32x4*       o4 = reinterpret_cast<f32x4*>(out) + base;

    int i = lane;
    #pragma unroll
    for (int k = 0; k < 6; ++k) {                  // covers lane + {0..11}*64
        f32x4 v0 = x4[i];
        f32x4 v1 = x4[i + 64];
        o4[i]      = v0 * gv;
        o4[i + 64] = v1 * gv;
        i += 128;
    }
    if (lane < 16)                                 // tail: 784 = 12*64 + 16
        o4[768 + lane] = x4[768 + lane] * gv;
}

// ---------------------------------------------------------------------------
extern "C" void kernel_launch(void* const* d_in, const int* in_sizes, int n_in,
                              void* d_out, int out_size, void* d_ws, size_t ws_size,
                              hipStream_t stream) {
    const float* x  = (const float*)d_in[0];
    const float* w1 = (const float*)d_in[1];
    const float* b1 = (const float*)d_in[2];
    const float* w2 = (const float*)d_in[3];
    const float* b2 = (const float*)d_in[4];
    float* out = (float*)d_out;

    float* s = (float*)d_ws;                       // [BB*CC] = 128 KB
    float* g = s + BB * CC;                        // [BB*CC] = 128 KB

    for (int grp = 0; grp < NGROUP; ++grp) {
        se_pool <<<PLANES_G / WPB, 256, 0, stream>>>(x, s, grp);
        se_fc   <<<GROUP_B, 256, 0, stream>>>(s, w1, b1, w2, b2, g, grp);
        se_scale<<<PLANES_G / WPB, 256, 0, stream>>>(x, g, out, grp);
    }
}

// Round 7
// 204.418 us; speedup vs baseline: 1.2364x; 1.2364x over previous
//
#include <hip/hip_runtime.h>
#include <math.h>

// Problem constants (fixed by setup_inputs)
#define BB 64
#define CC 512
#define CR 32
#define HW 3136
#define HW4 784                    // HW/4 float4 per plane
#define GROUP_B 32                 // batches per L3-resident group (205.6 MB < 256 MB L3)
#define NGROUP (BB / GROUP_B)      // 2
#define PLANES_G (GROUP_B * CC)    // 16384 planes per group
#define WPB 4                      // waves per block (256 threads)

typedef float f32x4 __attribute__((ext_vector_type(4)));

// ---------------------------------------------------------------------------
// Kernel 1: global average pool. One WAVE per plane (identical to R5-217us).
// ---------------------------------------------------------------------------
__global__ __launch_bounds__(256) void se_pool(const float* __restrict__ x,
                                               float* __restrict__ s, int group) {
    const int wave = threadIdx.x >> 6;
    const int lane = threadIdx.x & 63;
    const int p = group * PLANES_G + blockIdx.x * WPB + wave;
    const f32x4* x4 = reinterpret_cast<const f32x4*>(x) + (size_t)p * HW4;

    float acc = 0.0f;
    for (int i = lane; i < HW4; i += 64) {
        f32x4 v = x4[i];
        acc += (v.x + v.y) + (v.z + v.w);
    }
    #pragma unroll
    for (int off = 32; off > 0; off >>= 1)
        acc += __shfl_down(acc, off, 64);
    if (lane == 0)
        s[p] = acc * (1.0f / (float)HW);
}

// ---------------------------------------------------------------------------
// Kernel 2: FC bottleneck + sigmoid gate (identical to R5-217us).
// ---------------------------------------------------------------------------
__global__ __launch_bounds__(256) void se_fc(
    const float* __restrict__ s,
    const float* __restrict__ w1, const float* __restrict__ b1,
    const float* __restrict__ w2, const float* __restrict__ b2,
    float* __restrict__ g, int group)
{
    const int b = group * GROUP_B + blockIdx.x;
    const int t = threadIdx.x;
    __shared__ float s_sh[CC];
    __shared__ float h_sh[CR];

    s_sh[t]       = s[b * CC + t];
    s_sh[t + 256] = s[b * CC + t + 256];
    __syncthreads();

    const int r = t >> 3, part = t & 7;
    const float* wr = w1 + r * CC;
    float ha = 0.0f;
    #pragma unroll
    for (int k = 0; k < CC / 8; ++k) {
        const int c = part + 8 * k;
        ha = fmaf(s_sh[c], wr[c], ha);
    }
    ha += __shfl_down(ha, 4, 8);
    ha += __shfl_down(ha, 2, 8);
    ha += __shfl_down(ha, 1, 8);
    if (part == 0) h_sh[r] = fmaxf(ha + b1[r], 0.0f);
    __syncthreads();

    #pragma unroll
    for (int j = 0; j < 2; ++j) {
        const int c2 = t + j * 256;
        float a2 = b2[c2];
        const float* w2r = w2 + c2 * CR;
        #pragma unroll
        for (int rr = 0; rr < CR; ++rr)
            a2 = fmaf(h_sh[rr], w2r[rr], a2);
        g[b * CC + c2] = 1.0f / (1.0f + expf(-a2));
    }
}

// ---------------------------------------------------------------------------
// Kernel 3: scale. One WAVE per plane. CHANGED vs R5: load the ENTIRE plane
// into registers (12 x f32x4, one vmcnt wait point), then multiply, then
// issue all NT stores. Avoids interleaved load/store on the shared in-order
// vmcnt counter (each load-use otherwise waits on older stores' mem-acks).
// ---------------------------------------------------------------------------
__global__ __launch_bounds__(256) void se_scale(
    const float* __restrict__ x, const float* __restrict__ g,
    float* __restrict__ out, int group)
{
    const int wave = threadIdx.x >> 6;
    const int lane = threadIdx.x & 63;
    const int p = group * PLANES_G + blockIdx.x * WPB + wave;
    const float gv = g[p];                         // same addr across wave -> broadcast
    const size_t base = (size_t)p * HW4;
    const f32x4* x4 = reinterpret_cast<const f32x4*>(x) + base;
    f32x4*       o4 = reinterpret_cast<f32x4*>(out) + base;

    f32x4 v[12];
    #pragma unroll
    for (int k = 0; k < 12; ++k)                   // 12 independent loads
        v[k] = x4[lane + 64 * k];
    f32x4 vt;
    const bool tail = (lane < 16);                 // 784 = 12*64 + 16
    if (tail) vt = x4[768 + lane];

    #pragma unroll
    for (int k = 0; k < 12; ++k)
        v[k] *= gv;
    if (tail) vt *= gv;

    #pragma unroll
    for (int k = 0; k < 12; ++k)
        __builtin_nontemporal_store(v[k], &o4[lane + 64 * k]);
    if (tail) __builtin_nontemporal_store(vt, &o4[768 + lane]);
}

// ---------------------------------------------------------------------------
extern "C" void kernel_launch(void* const* d_in, const int* in_sizes, int n_in,
                              void* d_out, int out_size, void* d_ws, size_t ws_size,
                              hipStream_t stream) {
    const float* x  = (const float*)d_in[0];
    const float* w1 = (const float*)d_in[1];
    const float* b1 = (const float*)d_in[2];
    const float* w2 = (const float*)d_in[3];
    const float* b2 = (const float*)d_in[4];
    float* out = (float*)d_out;

    float* s = (float*)d_ws;                       // [BB*CC] = 128 KB
    float* g = s + BB * CC;                        // [BB*CC] = 128 KB

    for (int grp = 0; grp < NGROUP; ++grp) {
        se_pool <<<PLANES_G / WPB, 256, 0, stream>>>(x, s, grp);
        se_fc   <<<GROUP_B, 256, 0, stream>>>(s, w1, b1, w2, b2, g, grp);
        se_scale<<<PLANES_G / WPB, 256, 0, stream>>>(x, g, out, grp);
    }
}